// Round 17
// baseline (123.843 us; speedup 1.0000x reference)
//
#include <hip/hip_runtime.h>
#include <hip/hip_bf16.h>
#include <stdint.h>

typedef __bf16 bf16;
typedef __bf16 bf16x4 __attribute__((ext_vector_type(4)));
typedef __bf16 bf16x8 __attribute__((ext_vector_type(8)));
typedef float  f32x4  __attribute__((ext_vector_type(4)));

#define MFMA16(a,b,c) __builtin_amdgcn_mfma_f32_16x16x32_bf16((a),(b),(c),0,0,0)

#define TSEQ 2048
#define NE   1024
#define NE3  3072
#define NH   16
#define HD   64
#define MTOK 4096   // BATCH*TSEQ

#if defined(__has_builtin) && __has_builtin(__builtin_amdgcn_exp2f)
#define EXP2F(x) __builtin_amdgcn_exp2f(x)
#else
__device__ __forceinline__ float exp2_fast(float x) {
  float r; asm("v_exp_f32 %0, %1" : "=v"(r) : "v"(x)); return r;
}
#define EXP2F(x) exp2_fast(x)
#endif

// async global->LDS, 16B per lane; LDS dest = wave-uniform base + lane*16
__device__ __forceinline__ void gl_lds16(const bf16* g, bf16* l) {
  __builtin_amdgcn_global_load_lds(
      (const __attribute__((address_space(1))) void*)g,
      (__attribute__((address_space(3))) void*)l,
      16, 0, 0);
}

// ---------------- fused prep: x cast (blocks 0..4095) + weight prep (4096..5375) ----
__global__ __launch_bounds__(256) void k_prep(const float* __restrict__ x,
                                              const float* __restrict__ wq,
                                              const float* __restrict__ wk,
                                              const float* __restrict__ wv,
                                              const float* __restrict__ wp2,
                                              const float* __restrict__ wp1,
                                              bf16* __restrict__ xb,
                                              bf16* __restrict__ W3T,
                                              bf16* __restrict__ Wp2T,
                                              bf16* __restrict__ Wp1b) {
  const int id = blockIdx.x;
  if (id < 4096) {              // x cast, float4 per thread
    const int i = id * 256 + threadIdx.x;
    float4 v = reinterpret_cast<const float4*>(x)[i];
    bf16x4 o = { (bf16)v.x, (bf16)v.y, (bf16)v.z, (bf16)v.w };
    reinterpret_cast<bf16x4*>(xb)[i] = o;
    return;
  }
  __shared__ float tile[64][65];
  const int wid = id - 4096;
  const int z  = wid >> 8;
  const int by = (wid >> 4) & 15, bx = wid & 15;
  const int r0 = by * 64, c0 = bx * 64;
  const int lc = threadIdx.x & 63, lr0 = threadIdx.x >> 6;
  if (z == 4) {                 // straight cast wp1 -> Wp1b
#pragma unroll
    for (int i = 0; i < 16; ++i) {
      int lr = i*4 + lr0;
      Wp1b[(size_t)(r0 + lr)*1024 + c0 + lc] = (bf16)wp1[(size_t)(r0 + lr)*1024 + c0 + lc];
    }
    return;
  }
  const float* in = (z == 0) ? wq : (z == 1) ? wk : (z == 2) ? wv : wp2;
  bf16* out = (z < 3) ? (W3T + (size_t)z * 1024 * 1024) : Wp2T;
#pragma unroll
  for (int i = 0; i < 16; ++i) {
    int lr = i*4 + lr0;
    tile[lr][lc] = in[(size_t)(r0 + lr) * 1024 + (c0 + lc)];
  }
  __syncthreads();
#pragma unroll
  for (int i = 0; i < 16; ++i) {
    int lr = i*4 + lr0;
    out[(size_t)(c0 + lr) * 1024 + (r0 + lc)] = (bf16)tile[lc][lr];
  }
}

// ---------------- GEMM: C[M,N] = A[M,K] * Bt[N,K]^T, XCD-swizzled grid ----------------
// VTF: for the QKV GEMM, blocks with bn >= 2048 (V columns) write their C-tile
// directly TRANSPOSED to Vt[b*16+h][d][t] (bf16x4 along t) and skip the C write.
template<int BN, typename OutT, bool VTF>
__global__ __launch_bounds__(256) void k_gemm_bt(const bf16* __restrict__ A,
                                                 const bf16* __restrict__ Bt,
                                                 OutT* __restrict__ C,
                                                 bf16* __restrict__ VtOut,
                                                 const int M, const int N, const int K) {
  constexpr int NC = BN / 32;
  __shared__ bf16 As[2][128*32];
  __shared__ bf16 Bs[2][BN*32];
  const int tid  = threadIdx.x;
  const int lane = tid & 63;
  const int wave = tid >> 6;
  const int wr = (wave >> 1) * 64;
  const int wc = (wave & 1) * (BN/2);
  const int l15 = lane & 15;
  const int l4  = lane >> 4;

  const int nwg = gridDim.x * gridDim.y;
  int id = blockIdx.y * gridDim.x + blockIdx.x;
  id = (id & 7) * (nwg >> 3) + (id >> 3);
  const int bm = (id / gridDim.x) * 128;
  const int bn = (id % gridDim.x) * BN;

  const int srow = tid >> 2;
  const int scol = ((tid & 3) ^ ((tid >> 3) & 3)) * 8;
  const bf16* ag = A  + (size_t)(bm + srow) * K + scol;
  const bf16* bg = Bt + (size_t)(bn + srow) * K + scol;
  const int kx = (l4 ^ ((l15 >> 1) & 3)) * 8;

  f32x4 acc[4][NC] = {};

  auto stage = [&](int buf, int k0) {
    bf16* al = As[buf] + tid * 8;
    bf16* bl = Bs[buf] + tid * 8;
    gl_lds16(ag + k0,                   al);
    gl_lds16(ag + k0 + (size_t)64 * K,  al + 64*32);
    gl_lds16(bg + k0,                   bl);
    if (BN == 128) gl_lds16(bg + k0 + (size_t)64 * K, bl + 64*32);
  };

  stage(0, 0);
  __syncthreads();
  int cur = 0;
  for (int k0 = 0; k0 < K; k0 += 32) {
    if (k0 + 32 < K) stage(cur ^ 1, k0 + 32);
    bf16x8 af[4], bfr[NC];
#pragma unroll
    for (int m = 0; m < 4; ++m)
      af[m] = *reinterpret_cast<const bf16x8*>(&As[cur][(wr + m*16 + l15)*32 + kx]);
#pragma unroll
    for (int n = 0; n < NC; ++n)
      bfr[n] = *reinterpret_cast<const bf16x8*>(&Bs[cur][(wc + n*16 + l15)*32 + kx]);
#pragma unroll
    for (int m = 0; m < 4; ++m)
#pragma unroll
      for (int n = 0; n < NC; ++n)
        acc[m][n] = MFMA16(af[m], bfr[n], acc[m][n]);
    __syncthreads();
    cur ^= 1;
  }

  if (VTF && bn >= 2048) {
    const int bB  = bm >> 11;                 // batch (128 | 2048)
    const int tb0 = (bm & 2047) + wr + l4*4;
#pragma unroll
    for (int m = 0; m < 4; ++m) {
      const int tb = tb0 + m*16;
#pragma unroll
      for (int n = 0; n < NC; ++n) {
        const int dg = (bn - 2048) + wc + n*16 + l15;   // global V feature 0..1023
        bf16x4 ov;
#pragma unroll
        for (int r = 0; r < 4; ++r) ov[r] = (bf16)acc[m][n][r];
        *reinterpret_cast<bf16x4*>(
            &VtOut[((size_t)(bB*16 + (dg >> 6))*64 + (dg & 63))*2048 + tb]) = ov;
      }
    }
  } else {
#pragma unroll
    for (int m = 0; m < 4; ++m) {
      const int row = bm + wr + m*16 + l4*4;
#pragma unroll
      for (int n = 0; n < NC; ++n) {
        const int col = bn + wc + n*16 + l15;
#pragma unroll
        for (int r = 0; r < 4; ++r)
          C[(size_t)(row + r) * N + col] = (OutT)acc[m][n][r];
      }
    }
  }
}

// ---------------- out-projection GEMM: C[M,N] = A[M,K]*Bt[N,K]^T, BN=64, f32 out ----
__global__ __launch_bounds__(256) void k_gemm_out(const bf16* __restrict__ A,
                                                  const bf16* __restrict__ Bt,
                                                  float* __restrict__ C) {
  constexpr int K = 1024, N = 1024, BN = 64;
  __shared__ bf16 As[2][128*32];
  __shared__ bf16 Bs[2][BN*32];
  const int tid  = threadIdx.x;
  const int lane = tid & 63;
  const int wave = tid >> 6;
  const int wr = (wave >> 1) * 64;
  const int wc = (wave & 1) * 32;
  const int l15 = lane & 15;
  const int l4  = lane >> 4;

  const int nwg = gridDim.x * gridDim.y;
  int id = blockIdx.y * gridDim.x + blockIdx.x;
  id = (id & 7) * (nwg >> 3) + (id >> 3);
  const int bm = (id / gridDim.x) * 128;
  const int bn = (id % gridDim.x) * BN;

  const int srow = tid >> 2;
  const int scol = ((tid & 3) ^ ((tid >> 3) & 3)) * 8;
  const bf16* ag = A  + (size_t)(bm + srow) * K + scol;
  const bf16* bg = Bt + (size_t)(bn + srow) * K + scol;
  const int kx = (l4 ^ ((l15 >> 1) & 3)) * 8;

  f32x4 acc[4][2] = {};

  auto stage = [&](int buf, int k0) {
    bf16* al = As[buf] + tid * 8;
    bf16* bl = Bs[buf] + tid * 8;
    gl_lds16(ag + k0,                  al);
    gl_lds16(ag + k0 + (size_t)64 * K, al + 64*32);
    gl_lds16(bg + k0,                  bl);
  };

  stage(0, 0);
  __syncthreads();
  int cur = 0;
  for (int k0 = 0; k0 < K; k0 += 32) {
    if (k0 + 32 < K) stage(cur ^ 1, k0 + 32);
    bf16x8 af[4], bfr[2];
#pragma unroll
    for (int m = 0; m < 4; ++m)
      af[m] = *reinterpret_cast<const bf16x8*>(&As[cur][(wr + m*16 + l15)*32 + kx]);
#pragma unroll
    for (int n = 0; n < 2; ++n)
      bfr[n] = *reinterpret_cast<const bf16x8*>(&Bs[cur][(wc + n*16 + l15)*32 + kx]);
#pragma unroll
    for (int m = 0; m < 4; ++m)
#pragma unroll
      for (int n = 0; n < 2; ++n)
        acc[m][n] = MFMA16(af[m], bfr[n], acc[m][n]);
    __syncthreads();
    cur ^= 1;
  }

#pragma unroll
  for (int m = 0; m < 4; ++m) {
    const int row = bm + wr + m*16 + l4*4;
#pragma unroll
    for (int n = 0; n < 2; ++n) {
      const int col = bn + wc + n*16 + l15;
#pragma unroll
      for (int r = 0; r < 4; ++r)
        C[(size_t)(row + r) * N + col] = acc[m][n][r];
    }
  }
}

// ---------------- causal flash attention — R13 structure, KVBLK=256 (2 sub-passes) ----
// 256 blocks x 512 threads. Block (p, bh), p=0..7, q-chunks {p, 15-p} of 128 rows;
// wave owns 16 q-rows. KV tiles of 256, processed as two 128-kv sub-passes between
// one barrier pair; exactly 9 tile-iterations per block (ceil((p+2)/2)+ceil((17-p)/2)).
// Sub-pass 2t+h: skipped when 2t+h > c (block-uniform); diagonal when 2t+h == c.
// K LDS [2 ks][256 kv][32], V LDS [8 pt][64 d][32], granule-swizzled both sides;
// Ps per-wave buffer reused across sub-passes (same-wave DS ordering). LDS = 160KB.
__global__ __launch_bounds__(512) void k_attn(const bf16* __restrict__ QKV,
                                              const bf16* __restrict__ Vt,
                                              bf16* __restrict__ O) {
  __shared__ bf16 Ks[2][2*256*32];    // 2 x 32KB
  __shared__ bf16 Vs[2][8*64*32];     // 2 x 32KB
  __shared__ bf16 Ps[8][4*16*32];     // 8 x 4KB   (total 160KB)

  const int tid  = threadIdx.x;
  const int lane = tid & 63;
  const int wave = tid >> 6;          // 0..7
  const int l15 = lane & 15;
  const int l4  = lane >> 4;

  const int x  = blockIdx.x;          // 0..255
  const int p  = x >> 5;              // pair 0..7
  const int bh = x & 31;
  const int b  = bh >> 4, h = bh & 15;

  const bf16* Qb = QKV + (size_t)b*TSEQ*NE3 +        h*HD;
  const bf16* Kb = QKV + (size_t)b*TSEQ*NE3 + 1024 + h*HD;
  const bf16* Vb = Vt  + (size_t)bh*HD*TSEQ;
  bf16* Pw = Ps[wave];

  const float SC = 0.125f * 1.44269504f;
  const int swz = (l4 ^ ((l15 >> 1) & 3)) * 8;      // read-side swizzled granule (elems)
  const int key = (l15 >> 1) & 3;

  // staging maps (512 threads, 8 gl_lds16 each per 256-kv tile)
  const int krw = tid >> 2;                         // K row within round 0..127
  const int kg4 = tid & 3;
  const int vs  = tid & 255;                        // V slot within panel-pair
  const int vd  = vs >> 2;                          // d 0..63
  const int vg4 = vs & 3;
  const int vph = tid >> 8;                         // 0/1: panel parity

  const int ntc1 = (p + 2) >> 1;                    // tiles of first chunk
  auto tileOf = [&](int j) { return (j < ntc1) ? j : (j - ntc1); };

  auto stage = [&](int buf, int t) {
    // K: 2 ks panels x 256 rows x 32; per panel 2 rounds of 128 rows
#pragma unroll
    for (int kk = 0; kk < 2; ++kk)
#pragma unroll
      for (int rr = 0; rr < 2; ++rr) {
        const int r  = rr*128 + krw;
        const int gs = kg4 ^ ((r >> 1) & 3);
        gl_lds16(&Kb[(size_t)(t*256 + r)*NE3 + kk*32 + gs*8],
                 &Ks[buf][kk*8192 + rr*4096 + tid*8]);
      }
    // V: 8 panels x 64 d x 32; 4 rounds, panel = rv*2 + vph
#pragma unroll
    for (int rv = 0; rv < 4; ++rv) {
      const int pt = rv*2 + vph;
      const int gs = vg4 ^ ((vd >> 1) & 3);
      gl_lds16(&Vb[(size_t)vd*TSEQ + t*256 + pt*32 + gs*8],
               &Vs[buf][rv*4096 + tid*8]);
    }
  };

  stage(0, 0);
  __syncthreads();
  int cur = 0;
  int it = 0;                                       // tile iteration 0..8

  for (int ci = 0; ci < 2; ++ci) {
    const int c  = ci ? (15 - p) : p;               // active q-chunk (128 rows)
    const int qw = c*128 + wave*16;                 // this wave's first q row
    const int ntc = (c + 2) >> 1;                   // 256-kv tiles for this chunk

    bf16x8 qf[2];
#pragma unroll
    for (int ks = 0; ks < 2; ++ks) {
      bf16x8 qv = *reinterpret_cast<const bf16x8*>(
          &Qb[(size_t)(qw + l15)*NE3 + ks*32 + l4*8]);
#pragma unroll
      for (int j = 0; j < 8; ++j) qv[j] = (bf16)((float)qv[j] * SC);
      qf[ks] = qv;
    }

    f32x4 ot[4] = {};                  // O^T: row d = n2*16+l4*4+r, col q = qw+l15
    float m_run = -1e30f;
    float l_part = 0.f;

    for (int t = 0; t < ntc; ++t, ++it) {
      if (it + 1 < 9) stage(cur ^ 1, tileOf(it + 1));

#pragma unroll
      for (int hh = 0; hh < 2; ++hh) {
        const int sp = t*2 + hh;                    // 128-kv sub-pass index
        if (sp <= c) {                              // block-uniform causal skip
          // S^T[kv][q] = K Q^T   (128 kv x 16 q per wave)
          f32x4 st[8];
#pragma unroll
          for (int kvf = 0; kvf < 8; ++kvf) {
            st[kvf] = f32x4{0.f, 0.f, 0.f, 0.f};
            const int row = kvf*16 + l15;
#pragma unroll
            for (int ks = 0; ks < 2; ++ks) {
              bf16x8 kf = *reinterpret_cast<const bf16x8*>(
                  &Ks[cur][ks*8192 + hh*4096 + row*32 + swz]);
              st[kvf] = MFMA16(kf, qf[ks], st[kvf]);
            }
          }

          if (sp == c) {               // diagonal sub-pass: causal mask (tile-local)
#pragma unroll
            for (int kvf = 0; kvf < 8; ++kvf)
#pragma unroll
              for (int r = 0; r < 4; ++r)
                if (kvf*16 + l4*4 + r > wave*16 + l15) st[kvf][r] = -1e30f;
          }

          float mx = st[0][0];
#pragma unroll
          for (int kvf = 0; kvf < 8; ++kvf)
#pragma unroll
            for (int r = 0; r < 4; ++r) mx = fmaxf(mx, st[kvf][r]);
          mx = fmaxf(mx, __shfl_xor(mx, 16));
          mx = fmaxf(mx, __shfl_xor(mx, 32));

          if (__any(mx > m_run + 8.f)) {            // T13 defer-max
            const float mnew = fmaxf(m_run, mx);
            const float corr = EXP2F(m_run - mnew);
            l_part *= corr;
#pragma unroll
            for (int n2 = 0; n2 < 4; ++n2) ot[n2] *= corr;
            m_run = mnew;
          }

          float rs = 0.f;
#pragma unroll
          for (int kvf = 0; kvf < 8; ++kvf) {
            bf16x4 pk;
#pragma unroll
            for (int r = 0; r < 4; ++r) {
              const float pv = EXP2F(st[kvf][r] - m_run);
              rs += pv;
              pk[r] = (bf16)pv;
            }
            const int gp = (((kvf & 1)*2 + (l4 >> 1)) ^ key);
            *reinterpret_cast<bf16x4*>(
                &Pw[(kvf>>1)*512 + l15*32 + gp*8 + (l4 & 1)*4]) = pk;
          }
          l_part += rs;

          bf16x8 pa[4];
#pragma unroll
          for (int ksv = 0; ksv < 4; ++ksv)
            pa[ksv] = *reinterpret_cast<const bf16x8*>(&Pw[ksv*512 + l15*32 + swz]);
#pragma unroll
          for (int n2 = 0; n2 < 4; ++n2) {
            const int vrow = n2*16 + l15;
#pragma unroll
            for (int ksv = 0; ksv < 4; ++ksv) {
              bf16x8 vf = *reinterpret_cast<const bf16x8*>(
                  &Vs[cur][hh*8192 + ksv*2048 + vrow*32 + swz]);
              ot[n2] = MFMA16(vf, pa[ksv], ot[n2]);
            }
          }
        }
      }

      __syncthreads();
      cur ^= 1;
    }

    float l = l_part;
    l += __shfl_xor(l, 16);
    l += __shfl_xor(l, 32);
    const float rl = 1.f / l;
    const size_t row = (size_t)(b*TSEQ + qw + l15);
#pragma unroll
    for (int n2 = 0; n2 < 4; ++n2) {
      bf16x4 ov;
#pragma unroll
      for (int r = 0; r < 4; ++r) ov[r] = (bf16)(ot[n2][r] * rl);
      *reinterpret_cast<bf16x4*>(&O[row*NE + h*HD + n2*16 + l4*4]) = ov;
    }
  }
}

// ---------------- launch ----------------
extern "C" void kernel_launch(void* const* d_in, const int* in_sizes, int n_in,
                              void* d_out, int out_size, void* d_ws, size_t ws_size,
                              hipStream_t stream) {
  const float* x   = (const float*)d_in[0];
  const float* wq  = (const float*)d_in[1];
  const float* wk  = (const float*)d_in[2];
  const float* wv  = (const float*)d_in[3];
  const float* wp1 = (const float*)d_in[4];
  const float* wp2 = (const float*)d_in[5];
  float* out = (float*)d_out;

  char* ws = (char*)d_ws;
  const size_t MB = 1024ull * 1024ull;
  bf16* xb   = (bf16*)(ws + 0*MB);    // 8 MB  [4096][1024]
  bf16* W3T  = (bf16*)(ws + 8*MB);    // 6 MB  [3072][1024]
  bf16* wp1b = (bf16*)(ws + 14*MB);   // 2 MB  [1024 hd][1024 c]
  bf16* wp2T = (bf16*)(ws + 16*MB);   // 2 MB  [1024 e][1024 c]
  bf16* WcT  = (bf16*)(ws + 18*MB);   // 2 MB  [1024 e][1024 hd]
  bf16* QKVb = (bf16*)(ws + 20*MB);   // 24 MB [4096][3072] (V region unused)
  bf16* Vtb  = (bf16*)(ws + 44*MB);   // 8 MB  [b][h][d][t]
  bf16* attb = (bf16*)(ws + 52*MB);   // 8 MB  (total 60 MB)

  // fused prep: x cast + all weight transposes/casts (one dispatch)
  k_prep<<<5376, 256, 0, stream>>>(x, wq, wk, wv, wp2, wp1, xb, W3T, wp2T, wp1b);

  // fused projection weight: WcT[e][hd] = sum_c wp2T[e][c] * wp1b[hd][c]
  k_gemm_bt<64, bf16, false><<<dim3(16, 8), 256, 0, stream>>>(
      wp2T, wp1b, WcT, nullptr, 1024, 1024, 1024);

  // fused QKV projection; V columns written directly transposed to Vtb
  k_gemm_bt<128, bf16, true><<<dim3(24, 32), 256, 0, stream>>>(
      xb, W3T, QKVb, Vtb, MTOK, NE3, NE);

  // balanced causal flash attention (KVBLK=256, 9 iterations)
  k_attn<<<dim3(256), 512, 0, stream>>>(QKVb, Vtb, attb);

  // single fused output projection: out = att * Wc
  k_gemm_out<<<dim3(16, 32), 256, 0, stream>>>(attb, WcT, out);
}

// Round 18
// 122.100 us; speedup vs baseline: 1.0143x; 1.0143x over previous
//
#include <hip/hip_runtime.h>
#include <hip/hip_bf16.h>
#include <stdint.h>

typedef __bf16 bf16;
typedef __bf16 bf16x4 __attribute__((ext_vector_type(4)));
typedef __bf16 bf16x8 __attribute__((ext_vector_type(8)));
typedef float  f32x4  __attribute__((ext_vector_type(4)));

#define MFMA16(a,b,c) __builtin_amdgcn_mfma_f32_16x16x32_bf16((a),(b),(c),0,0,0)

#define TSEQ 2048
#define NE   1024
#define NE3  3072
#define NH   16
#define HD   64
#define MTOK 4096   // BATCH*TSEQ

#if defined(__has_builtin) && __has_builtin(__builtin_amdgcn_exp2f)
#define EXP2F(x) __builtin_amdgcn_exp2f(x)
#else
__device__ __forceinline__ float exp2_fast(float x) {
  float r; asm("v_exp_f32 %0, %1" : "=v"(r) : "v"(x)); return r;
}
#define EXP2F(x) exp2_fast(x)
#endif

// async global->LDS, 16B per lane; LDS dest = wave-uniform base + lane*16
__device__ __forceinline__ void gl_lds16(const bf16* g, bf16* l) {
  __builtin_amdgcn_global_load_lds(
      (const __attribute__((address_space(1))) void*)g,
      (__attribute__((address_space(3))) void*)l,
      16, 0, 0);
}

// ---------------- fused prep: x cast (blocks 0..4095) + weight prep (4096..5375) ----
__global__ __launch_bounds__(256) void k_prep(const float* __restrict__ x,
                                              const float* __restrict__ wq,
                                              const float* __restrict__ wk,
                                              const float* __restrict__ wv,
                                              const float* __restrict__ wp2,
                                              const float* __restrict__ wp1,
                                              bf16* __restrict__ xb,
                                              bf16* __restrict__ W3T,
                                              bf16* __restrict__ Wp2T,
                                              bf16* __restrict__ Wp1b) {
  const int id = blockIdx.x;
  if (id < 4096) {              // x cast, float4 per thread
    const int i = id * 256 + threadIdx.x;
    float4 v = reinterpret_cast<const float4*>(x)[i];
    bf16x4 o = { (bf16)v.x, (bf16)v.y, (bf16)v.z, (bf16)v.w };
    reinterpret_cast<bf16x4*>(xb)[i] = o;
    return;
  }
  __shared__ float tile[64][65];
  const int wid = id - 4096;
  const int z  = wid >> 8;
  const int by = (wid >> 4) & 15, bx = wid & 15;
  const int r0 = by * 64, c0 = bx * 64;
  const int lc = threadIdx.x & 63, lr0 = threadIdx.x >> 6;
  if (z == 4) {                 // straight cast wp1 -> Wp1b
#pragma unroll
    for (int i = 0; i < 16; ++i) {
      int lr = i*4 + lr0;
      Wp1b[(size_t)(r0 + lr)*1024 + c0 + lc] = (bf16)wp1[(size_t)(r0 + lr)*1024 + c0 + lc];
    }
    return;
  }
  const float* in = (z == 0) ? wq : (z == 1) ? wk : (z == 2) ? wv : wp2;
  bf16* out = (z < 3) ? (W3T + (size_t)z * 1024 * 1024) : Wp2T;
#pragma unroll
  for (int i = 0; i < 16; ++i) {
    int lr = i*4 + lr0;
    tile[lr][lc] = in[(size_t)(r0 + lr) * 1024 + (c0 + lc)];
  }
  __syncthreads();
#pragma unroll
  for (int i = 0; i < 16; ++i) {
    int lr = i*4 + lr0;
    out[(size_t)(c0 + lr) * 1024 + (r0 + lc)] = (bf16)tile[lc][lr];
  }
}

// ---------------- GEMM: C[M,N] = A[M,K] * Bt[N,K]^T, XCD-swizzled grid ----------------
// VTF: for the QKV GEMM, blocks with bn >= 2048 (V columns) write their C-tile
// directly TRANSPOSED to Vt[b*16+h][d][t] (bf16x4 along t) and skip the C write.
template<int BN, typename OutT, bool VTF>
__global__ __launch_bounds__(256) void k_gemm_bt(const bf16* __restrict__ A,
                                                 const bf16* __restrict__ Bt,
                                                 OutT* __restrict__ C,
                                                 bf16* __restrict__ VtOut,
                                                 const int M, const int N, const int K) {
  constexpr int NC = BN / 32;
  __shared__ bf16 As[2][128*32];
  __shared__ bf16 Bs[2][BN*32];
  const int tid  = threadIdx.x;
  const int lane = tid & 63;
  const int wave = tid >> 6;
  const int wr = (wave >> 1) * 64;
  const int wc = (wave & 1) * (BN/2);
  const int l15 = lane & 15;
  const int l4  = lane >> 4;

  const int nwg = gridDim.x * gridDim.y;
  int id = blockIdx.y * gridDim.x + blockIdx.x;
  id = (id & 7) * (nwg >> 3) + (id >> 3);
  const int bm = (id / gridDim.x) * 128;
  const int bn = (id % gridDim.x) * BN;

  const int srow = tid >> 2;
  const int scol = ((tid & 3) ^ ((tid >> 3) & 3)) * 8;
  const bf16* ag = A  + (size_t)(bm + srow) * K + scol;
  const bf16* bg = Bt + (size_t)(bn + srow) * K + scol;
  const int kx = (l4 ^ ((l15 >> 1) & 3)) * 8;

  f32x4 acc[4][NC] = {};

  auto stage = [&](int buf, int k0) {
    bf16* al = As[buf] + tid * 8;
    bf16* bl = Bs[buf] + tid * 8;
    gl_lds16(ag + k0,                   al);
    gl_lds16(ag + k0 + (size_t)64 * K,  al + 64*32);
    gl_lds16(bg + k0,                   bl);
    if (BN == 128) gl_lds16(bg + k0 + (size_t)64 * K, bl + 64*32);
  };

  stage(0, 0);
  __syncthreads();
  int cur = 0;
  for (int k0 = 0; k0 < K; k0 += 32) {
    if (k0 + 32 < K) stage(cur ^ 1, k0 + 32);
    bf16x8 af[4], bfr[NC];
#pragma unroll
    for (int m = 0; m < 4; ++m)
      af[m] = *reinterpret_cast<const bf16x8*>(&As[cur][(wr + m*16 + l15)*32 + kx]);
#pragma unroll
    for (int n = 0; n < NC; ++n)
      bfr[n] = *reinterpret_cast<const bf16x8*>(&Bs[cur][(wc + n*16 + l15)*32 + kx]);
#pragma unroll
    for (int m = 0; m < 4; ++m)
#pragma unroll
      for (int n = 0; n < NC; ++n)
        acc[m][n] = MFMA16(af[m], bfr[n], acc[m][n]);
    __syncthreads();
    cur ^= 1;
  }

  if (VTF && bn >= 2048) {
    const int bB  = bm >> 11;                 // batch (128 | 2048)
    const int tb0 = (bm & 2047) + wr + l4*4;
#pragma unroll
    for (int m = 0; m < 4; ++m) {
      const int tb = tb0 + m*16;
#pragma unroll
      for (int n = 0; n < NC; ++n) {
        const int dg = (bn - 2048) + wc + n*16 + l15;   // global V feature 0..1023
        bf16x4 ov;
#pragma unroll
        for (int r = 0; r < 4; ++r) ov[r] = (bf16)acc[m][n][r];
        *reinterpret_cast<bf16x4*>(
            &VtOut[((size_t)(bB*16 + (dg >> 6))*64 + (dg & 63))*2048 + tb]) = ov;
      }
    }
  } else {
#pragma unroll
    for (int m = 0; m < 4; ++m) {
      const int row = bm + wr + m*16 + l4*4;
#pragma unroll
      for (int n = 0; n < NC; ++n) {
        const int col = bn + wc + n*16 + l15;
#pragma unroll
        for (int r = 0; r < 4; ++r)
          C[(size_t)(row + r) * N + col] = (OutT)acc[m][n][r];
      }
    }
  }
}

// ---------------- out-projection GEMM: C[M,N] = A[M,K]*Bt[N,K]^T, BN=64, f32 out ----
__global__ __launch_bounds__(256) void k_gemm_out(const bf16* __restrict__ A,
                                                  const bf16* __restrict__ Bt,
                                                  float* __restrict__ C) {
  constexpr int K = 1024, N = 1024, BN = 64;
  __shared__ bf16 As[2][128*32];
  __shared__ bf16 Bs[2][BN*32];
  const int tid  = threadIdx.x;
  const int lane = tid & 63;
  const int wave = tid >> 6;
  const int wr = (wave >> 1) * 64;
  const int wc = (wave & 1) * 32;
  const int l15 = lane & 15;
  const int l4  = lane >> 4;

  const int nwg = gridDim.x * gridDim.y;
  int id = blockIdx.y * gridDim.x + blockIdx.x;
  id = (id & 7) * (nwg >> 3) + (id >> 3);
  const int bm = (id / gridDim.x) * 128;
  const int bn = (id % gridDim.x) * BN;

  const int srow = tid >> 2;
  const int scol = ((tid & 3) ^ ((tid >> 3) & 3)) * 8;
  const bf16* ag = A  + (size_t)(bm + srow) * K + scol;
  const bf16* bg = Bt + (size_t)(bn + srow) * K + scol;
  const int kx = (l4 ^ ((l15 >> 1) & 3)) * 8;

  f32x4 acc[4][2] = {};

  auto stage = [&](int buf, int k0) {
    bf16* al = As[buf] + tid * 8;
    bf16* bl = Bs[buf] + tid * 8;
    gl_lds16(ag + k0,                  al);
    gl_lds16(ag + k0 + (size_t)64 * K, al + 64*32);
    gl_lds16(bg + k0,                  bl);
  };

  stage(0, 0);
  __syncthreads();
  int cur = 0;
  for (int k0 = 0; k0 < K; k0 += 32) {
    if (k0 + 32 < K) stage(cur ^ 1, k0 + 32);
    bf16x8 af[4], bfr[2];
#pragma unroll
    for (int m = 0; m < 4; ++m)
      af[m] = *reinterpret_cast<const bf16x8*>(&As[cur][(wr + m*16 + l15)*32 + kx]);
#pragma unroll
    for (int n = 0; n < 2; ++n)
      bfr[n] = *reinterpret_cast<const bf16x8*>(&Bs[cur][(wc + n*16 + l15)*32 + kx]);
#pragma unroll
    for (int m = 0; m < 4; ++m)
#pragma unroll
      for (int n = 0; n < 2; ++n)
        acc[m][n] = MFMA16(af[m], bfr[n], acc[m][n]);
    __syncthreads();
    cur ^= 1;
  }

#pragma unroll
  for (int m = 0; m < 4; ++m) {
    const int row = bm + wr + m*16 + l4*4;
#pragma unroll
    for (int n = 0; n < 2; ++n) {
      const int col = bn + wc + n*16 + l15;
#pragma unroll
      for (int r = 0; r < 4; ++r)
        C[(size_t)(row + r) * N + col] = acc[m][n][r];
    }
  }
}

// ---------------- causal flash attention — R6/R13 structure (best measured) ----------
// 256 blocks x 512 threads. Block (p, bh), p=0..7, processes q-chunks {p, 15-p} of
// 128 rows; wave owns 16 q-rows. Exactly 17 KV-tile iterations per block (KVBLK=128).
// K LDS [2 ks][128 kv][32], V LDS [4 ksv][64 d][32], granule-swizzled both sides,
// double-buffered (stage-ahead + __syncthreads). Swapped QK^T (S^T), O^T accumulation,
// T13 defer-max, per-wave Ps. Straight-line loop body — measured optimum across 11
// variants (pipeline depth, 32x32, kv-split, block-split, branch-skip, setprio,
// KVBLK=256 all neutral or worse, R7-R17).
__global__ __launch_bounds__(512) void k_attn(const bf16* __restrict__ QKV,
                                              const bf16* __restrict__ Vt,
                                              bf16* __restrict__ O) {
  __shared__ bf16 Ks[2][2*128*32];    // 2 x 16KB
  __shared__ bf16 Vs[2][4*64*32];     // 2 x 16KB
  __shared__ bf16 Ps[8][4*16*32];     // 8 x 4KB

  const int tid  = threadIdx.x;
  const int lane = tid & 63;
  const int wave = tid >> 6;          // 0..7
  const int l15 = lane & 15;
  const int l4  = lane >> 4;

  const int x  = blockIdx.x;          // 0..255
  const int p  = x >> 5;              // pair 0..7
  const int bh = x & 31;
  const int b  = bh >> 4, h = bh & 15;

  const bf16* Qb = QKV + (size_t)b*TSEQ*NE3 +        h*HD;
  const bf16* Kb = QKV + (size_t)b*TSEQ*NE3 + 1024 + h*HD;
  const bf16* Vb = Vt  + (size_t)bh*HD*TSEQ;
  bf16* Pw = Ps[wave];

  const float SC = 0.125f * 1.44269504f;
  const int swz = (l4 ^ ((l15 >> 1) & 3)) * 8;      // read-side swizzled granule (elems)
  const int key = (l15 >> 1) & 3;

  const int krow = tid >> 2;                        // 0..127
  const int kg   = (tid & 3) ^ ((krow >> 1) & 3);
  const int vd   = (tid >> 2) & 63;
  const int vg   = (tid & 3) ^ ((vd >> 1) & 3);
  const int vp0  = tid >> 8;                        // 0 or 1

  auto stage = [&](int buf, int t) {
#pragma unroll
    for (int kk = 0; kk < 2; ++kk)
      gl_lds16(&Kb[(size_t)(t*128 + krow)*NE3 + kk*32 + kg*8],
               &Ks[buf][kk*4096 + tid*8]);
#pragma unroll
    for (int kk = 0; kk < 2; ++kk) {
      const int ksv = kk*2 + vp0;
      gl_lds16(&Vb[(size_t)vd*TSEQ + t*128 + ksv*32 + vg*8],
               &Vs[buf][kk*4096 + tid*8]);
    }
  };

  stage(0, 0);
  __syncthreads();
  int cur = 0;
  int i = 0;                                        // global iteration 0..16

  for (int ci = 0; ci < 2; ++ci) {
    const int c  = ci ? (15 - p) : p;               // active q-chunk (128 rows)
    const int qw = c*128 + wave*16;                 // this wave's first q row

    bf16x8 qf[2];
#pragma unroll
    for (int ks = 0; ks < 2; ++ks) {
      bf16x8 qv = *reinterpret_cast<const bf16x8*>(
          &Qb[(size_t)(qw + l15)*NE3 + ks*32 + l4*8]);
#pragma unroll
      for (int j = 0; j < 8; ++j) qv[j] = (bf16)((float)qv[j] * SC);
      qf[ks] = qv;
    }

    f32x4 ot[4] = {};                  // O^T: row d = n2*16+l4*4+r, col q = qw+l15
    float m_run = -1e30f;
    float l_part = 0.f;

    for (int t = 0; t <= c; ++t, ++i) {
      if (i + 1 < 17) {
        const int nxt = (i + 1 <= p) ? (i + 1) : (i - p);
        stage(cur ^ 1, nxt);
      }

      f32x4 st[8];
#pragma unroll
      for (int kvf = 0; kvf < 8; ++kvf) {
        st[kvf] = f32x4{0.f, 0.f, 0.f, 0.f};
        const int row = kvf*16 + l15;
#pragma unroll
        for (int ks = 0; ks < 2; ++ks) {
          bf16x8 kf = *reinterpret_cast<const bf16x8*>(&Ks[cur][ks*4096 + row*32 + swz]);
          st[kvf] = MFMA16(kf, qf[ks], st[kvf]);
        }
      }

      if (t == c) {                    // diagonal tile: causal mask (tile-local)
#pragma unroll
        for (int kvf = 0; kvf < 8; ++kvf)
#pragma unroll
          for (int r = 0; r < 4; ++r)
            if (kvf*16 + l4*4 + r > wave*16 + l15) st[kvf][r] = -1e30f;
      }

      float mx = st[0][0];
#pragma unroll
      for (int kvf = 0; kvf < 8; ++kvf)
#pragma unroll
        for (int r = 0; r < 4; ++r) mx = fmaxf(mx, st[kvf][r]);
      mx = fmaxf(mx, __shfl_xor(mx, 16));
      mx = fmaxf(mx, __shfl_xor(mx, 32));

      if (__any(mx > m_run + 8.f)) {   // T13 defer-max
        const float mnew = fmaxf(m_run, mx);
        const float corr = EXP2F(m_run - mnew);
        l_part *= corr;
#pragma unroll
        for (int n2 = 0; n2 < 4; ++n2) ot[n2] *= corr;
        m_run = mnew;
      }

      float rs = 0.f;
#pragma unroll
      for (int kvf = 0; kvf < 8; ++kvf) {
        bf16x4 pk;
#pragma unroll
        for (int r = 0; r < 4; ++r) {
          const float pv = EXP2F(st[kvf][r] - m_run);
          rs += pv;
          pk[r] = (bf16)pv;
        }
        const int gp = (((kvf & 1)*2 + (l4 >> 1)) ^ key);
        *reinterpret_cast<bf16x4*>(
            &Pw[(kvf>>1)*512 + l15*32 + gp*8 + (l4 & 1)*4]) = pk;
      }
      l_part += rs;

      bf16x8 pa[4];
#pragma unroll
      for (int ksv = 0; ksv < 4; ++ksv)
        pa[ksv] = *reinterpret_cast<const bf16x8*>(&Pw[ksv*512 + l15*32 + swz]);
#pragma unroll
      for (int n2 = 0; n2 < 4; ++n2) {
        const int vrow = n2*16 + l15;
#pragma unroll
        for (int ksv = 0; ksv < 4; ++ksv) {
          bf16x8 vf = *reinterpret_cast<const bf16x8*>(&Vs[cur][ksv*2048 + vrow*32 + swz]);
          ot[n2] = MFMA16(vf, pa[ksv], ot[n2]);
        }
      }

      __syncthreads();
      cur ^= 1;
    }

    float l = l_part;
    l += __shfl_xor(l, 16);
    l += __shfl_xor(l, 32);
    const float rl = 1.f / l;
    const size_t row = (size_t)(b*TSEQ + qw + l15);
#pragma unroll
    for (int n2 = 0; n2 < 4; ++n2) {
      bf16x4 ov;
#pragma unroll
      for (int r = 0; r < 4; ++r) ov[r] = (bf16)(ot[n2][r] * rl);
      *reinterpret_cast<bf16x4*>(&O[row*NE + h*HD + n2*16 + l4*4]) = ov;
    }
  }
}

// ---------------- launch ----------------
extern "C" void kernel_launch(void* const* d_in, const int* in_sizes, int n_in,
                              void* d_out, int out_size, void* d_ws, size_t ws_size,
                              hipStream_t stream) {
  const float* x   = (const float*)d_in[0];
  const float* wq  = (const float*)d_in[1];
  const float* wk  = (const float*)d_in[2];
  const float* wv  = (const float*)d_in[3];
  const float* wp1 = (const float*)d_in[4];
  const float* wp2 = (const float*)d_in[5];
  float* out = (float*)d_out;

  char* ws = (char*)d_ws;
  const size_t MB = 1024ull * 1024ull;
  bf16* xb   = (bf16*)(ws + 0*MB);    // 8 MB  [4096][1024]
  bf16* W3T  = (bf16*)(ws + 8*MB);    // 6 MB  [3072][1024]
  bf16* wp1b = (bf16*)(ws + 14*MB);   // 2 MB  [1024 hd][1024 c]
  bf16* wp2T = (bf16*)(ws + 16*MB);   // 2 MB  [1024 e][1024 c]
  bf16* WcT  = (bf16*)(ws + 18*MB);   // 2 MB  [1024 e][1024 hd]
  bf16* QKVb = (bf16*)(ws + 20*MB);   // 24 MB [4096][3072] (V region unused)
  bf16* Vtb  = (bf16*)(ws + 44*MB);   // 8 MB  [b][h][d][t]
  bf16* attb = (bf16*)(ws + 52*MB);   // 8 MB  (total 60 MB)

  // fused prep: x cast + all weight transposes/casts (one dispatch)
  k_prep<<<5376, 256, 0, stream>>>(x, wq, wk, wv, wp2, wp1, xb, W3T, wp2T, wp1b);

  // fused projection weight: WcT[e][hd] = sum_c wp2T[e][c] * wp1b[hd][c]
  k_gemm_bt<64, bf16, false><<<dim3(16, 8), 256, 0, stream>>>(
      wp2T, wp1b, WcT, nullptr, 1024, 1024, 1024);

  // fused QKV projection; V columns written directly transposed to Vtb
  k_gemm_bt<128, bf16, true><<<dim3(24, 32), 256, 0, stream>>>(
      xb, W3T, QKVb, Vtb, MTOK, NE3, NE);

  // balanced causal flash attention (R6/R13 structure)
  k_attn<<<dim3(256), 512, 0, stream>>>(QKVb, Vtb, attb);

  // single fused output projection: out = att * Wc
  k_gemm_out<<<dim3(16, 32), 256, 0, stream>>>(attb, WcT, out);
}